// Round 5
// baseline (236.691 us; speedup 1.0000x reference)
//
#include <hip/hip_runtime.h>

#define BDIM 256

constexpr int K      = 32;
constexpr int L1     = 1024;
constexpr int L2C    = 15;
constexpr int L3C    = 32;
constexpr int COUNT  = 9;
constexpr int NF     = 22528;
constexpr int W1COLS = COUNT * (L2C + 1); // 144
constexpr int W2COLS = COUNT * L3C;       // 288

__device__ __forceinline__ float clip01(float x) {
    return fminf(fmaxf(x, 0.0f), 1.0f);
}

// ---- fp32 -> uint8 (excess-128) per-row quantization of W_ft ----
// One wave per row: butterfly-shfl absmax, quantize, pack 4 B/lane/chunk.
// Rebuilt every iteration (workspace re-poisoned; ~25-30 us, near stream floor).
__global__ __launch_bounds__(256) void quant_w_ft(const float* __restrict__ src,
                                                  unsigned char* __restrict__ dst,
                                                  float* __restrict__ scales,
                                                  int nrows) {
    const int wq   = threadIdx.x >> 6;          // wave in block
    const int lane = threadIdx.x & 63;
    const int row  = blockIdx.x * 4 + wq;
    if (row >= nrows) return;

    const float* s = src + (long)row * L1;
    float4 v[4];
    float m = 0.0f;
    #pragma unroll
    for (int i = 0; i < 4; ++i) {
        v[i] = *(const float4*)(s + i * 256 + lane * 4);
        m = fmaxf(m, fmaxf(fmaxf(fabsf(v[i].x), fabsf(v[i].y)),
                           fmaxf(fabsf(v[i].z), fabsf(v[i].w))));
    }
    #pragma unroll
    for (int off = 32; off >= 1; off >>= 1)
        m = fmaxf(m, __shfl_xor(m, off));

    const float mm    = fmaxf(m, 1e-30f);
    const float scale = mm / 127.0f;
    const float inv   = 127.0f / mm;

    unsigned char* d = dst + (long)row * L1;
    #pragma unroll
    for (int i = 0; i < 4; ++i) {
        int q0 = (int)rintf(v[i].x * inv) + 128;
        int q1 = (int)rintf(v[i].y * inv) + 128;
        int q2 = (int)rintf(v[i].z * inv) + 128;
        int q3 = (int)rintf(v[i].w * inv) + 128;
        q0 = max(0, min(255, q0)); q1 = max(0, min(255, q1));
        q2 = max(0, min(255, q2)); q3 = max(0, min(255, q3));
        const unsigned pk = (unsigned)q0 | ((unsigned)q1 << 8) |
                            ((unsigned)q2 << 16) | ((unsigned)q3 << 24);
        *(unsigned*)(d + i * 256 + lane * 4) = pk;
    }
    if (lane == 0) scales[row] = scale;
}

// ---- fused NNUE forward, uint8 table, 16 B/lane gather ----
// R5: gather was VMEM-issue-bound at 8 B/lane (R4: 71 us vs 46 predicted;
// instruction count didn't drop fp16->int8). Restore 16 B/lane by splitting
// K across wave pairs: wave w -> persp = w>>1, k-half = w&1. One wave-load
// = 64 lanes x 16 B = exactly one 1 KB row, perfectly coalesced; 16 loads
// per thread (was 32). Partials combined via LDS s_part[persp][khalf][col].
__global__ __launch_bounds__(BDIM) void nnue_fused_q(
    const float* __restrict__ us,
    const float* __restrict__ them,
    const int*   __restrict__ wi,
    const float* __restrict__ wv,
    const int*   __restrict__ bi,
    const float* __restrict__ bvv,
    const int*   __restrict__ lsi,
    const unsigned char* __restrict__ Wq,
    const float* __restrict__ scl,
    const float* __restrict__ b_ft,
    const float* __restrict__ W1,
    const float* __restrict__ b1,
    const float* __restrict__ W2,
    const float* __restrict__ b2,
    const float* __restrict__ W3,
    const float* __restrict__ b3,
    float* __restrict__ out)
{
    const int b = blockIdx.x;
    const int t = threadIdx.x;

    __shared__ int   s_idx[2 * K];
    __shared__ float s_val[2 * K];           // val * scale[row]
    __shared__ float s_part[2][2][L1];       // [persp][khalf][col] partials
    __shared__ float s_red[4 * 16];
    __shared__ float s_v[2 * L2C];
    __shared__ float s_p2[L3C];
    __shared__ float s_l1f;

    // ---- stage sparse indices/values (scale folded into value) ----
    if (t < K) {
        const int ii = wi[b * K + t];
        s_idx[t] = ii;
        s_val[t] = wv[b * K + t] * scl[ii];
    } else if (t < 2 * K) {
        const int ii = bi[b * K + (t - K)];
        s_idx[t] = ii;
        s_val[t] = bvv[b * K + (t - K)] * scl[ii];
    }
    __syncthreads();

    // ---- feature transform ----
    const int w     = t >> 6;        // wave 0..3
    const int l     = t & 63;
    const int persp = w >> 1;        // 0 = white, 1 = black
    const int kh    = w & 1;         // k-half
    const int c16   = l * 16;        // 16 cols per lane

    const int*   idxs = s_idx + persp * K + kh * 16;
    const float* vals = s_val + persp * K + kh * 16;

    float acc[16];
    if (kh == 0) {
        #pragma unroll
        for (int j = 0; j < 16; j += 4) {
            const float4 bf = *(const float4*)(b_ft + c16 + j);
            acc[j] = bf.x; acc[j + 1] = bf.y; acc[j + 2] = bf.z; acc[j + 3] = bf.w;
        }
    } else {
        #pragma unroll
        for (int j = 0; j < 16; ++j) acc[j] = 0.0f;
    }

    float sumvs = 0.0f;
    #pragma unroll 8
    for (int k = 0; k < 16; ++k) {
        const float vs = vals[k];
        const uint4 q  = *(const uint4*)(Wq + ((long)idxs[k] << 10) + c16);
        sumvs += vs;
        acc[0]  = fmaf(vs, (float)( q.x        & 0xffu), acc[0]);
        acc[1]  = fmaf(vs, (float)((q.x >>  8) & 0xffu), acc[1]);
        acc[2]  = fmaf(vs, (float)((q.x >> 16) & 0xffu), acc[2]);
        acc[3]  = fmaf(vs, (float)( q.x >> 24        ), acc[3]);
        acc[4]  = fmaf(vs, (float)( q.y        & 0xffu), acc[4]);
        acc[5]  = fmaf(vs, (float)((q.y >>  8) & 0xffu), acc[5]);
        acc[6]  = fmaf(vs, (float)((q.y >> 16) & 0xffu), acc[6]);
        acc[7]  = fmaf(vs, (float)( q.y >> 24        ), acc[7]);
        acc[8]  = fmaf(vs, (float)( q.z        & 0xffu), acc[8]);
        acc[9]  = fmaf(vs, (float)((q.z >>  8) & 0xffu), acc[9]);
        acc[10] = fmaf(vs, (float)((q.z >> 16) & 0xffu), acc[10]);
        acc[11] = fmaf(vs, (float)( q.z >> 24        ), acc[11]);
        acc[12] = fmaf(vs, (float)( q.w        & 0xffu), acc[12]);
        acc[13] = fmaf(vs, (float)((q.w >>  8) & 0xffu), acc[13]);
        acc[14] = fmaf(vs, (float)((q.w >> 16) & 0xffu), acc[14]);
        acc[15] = fmaf(vs, (float)( q.w >> 24        ), acc[15]);
    }
    // remove excess-128 bias for this wave's k-half
    #pragma unroll
    for (int j = 0; j < 16; ++j) acc[j] = fmaf(sumvs, -128.0f, acc[j]);

    {
        float* dst = &s_part[persp][kh][c16];
        #pragma unroll
        for (int j = 0; j < 16; ++j) dst[j] = acc[j];
    }
    __syncthreads();

    const float u   = us[b];
    const float th  = them[b];
    const int   idx = lsi[b];
    const float cc  = 127.0f / 128.0f;

    #define WP(e) (s_part[0][0][(e)] + s_part[0][1][(e)])
    #define BP(e) (s_part[1][0][(e)] + s_part[1][1][(e)])

    // ---- layer 1: x1[j] = l0p . W1[:, idx*16 + j] ----
    float p[16];
    #pragma unroll
    for (int j = 0; j < 16; ++j) p[j] = 0.0f;

    const float* W1sel = W1 + idx * (L2C + 1);
    const int e0 = t * 4;
    #pragma unroll
    for (int q = 0; q < 4; ++q) {
        const int e = e0 + q;
        float l0p;
        if (e < 512) {
            const float a0 = clip01(u * WP(e)       + th * BP(e));
            const float a1 = clip01(u * WP(e + 512) + th * BP(e + 512));
            l0p = a0 * a1;
        } else {
            const int   c   = e - 512;
            const float b0  = clip01(u * BP(c) + th * WP(c));
            const float b1v = clip01(u * BP(e) + th * WP(e));
            l0p = b0 * b1v;
        }
        l0p *= cc;
        const float* wrow = W1sel + e * W1COLS;
        #pragma unroll
        for (int j = 0; j < 16; ++j) p[j] = fmaf(l0p, wrow[j], p[j]);
    }
    #undef WP
    #undef BP

    const int lane = t & 63;
    const int wid  = t >> 6;
    #pragma unroll
    for (int j = 0; j < 16; ++j) {
        float v = p[j];
        v += __shfl_down(v, 32);
        v += __shfl_down(v, 16);
        v += __shfl_down(v, 8);
        v += __shfl_down(v, 4);
        v += __shfl_down(v, 2);
        v += __shfl_down(v, 1);
        if (lane == 0) s_red[wid * 16 + j] = v;
    }
    __syncthreads();

    if (t < 16) {
        float x1 = s_red[t] + s_red[16 + t] + s_red[32 + t] + s_red[48 + t]
                 + b1[idx * (L2C + 1) + t];
        if (t == 15) {
            s_l1f = x1;
        } else {
            float cx = clip01(x1);
            s_v[t]       = cx * cx * cc;
            s_v[L2C + t] = cx * cc;
        }
    }
    __syncthreads();

    if (t < L3C) {
        float acc2 = b2[idx * L3C + t];
        #pragma unroll
        for (int r = 0; r < 2 * L2C; ++r)
            acc2 = fmaf(s_v[r], W2[r * W2COLS + idx * L3C + t], acc2);
        s_p2[t] = clip01(acc2) * W3[t * COUNT + idx];
    }
    __syncthreads();

    if (t == 0) {
        float s = 0.0f;
        #pragma unroll
        for (int m = 0; m < L3C; ++m) s += s_p2[m];
        out[b] = s + b3[idx] + s_l1f;
    }
}

// ---- fp32 single-kernel fallback (ws too small) — verified 186 us ----
__global__ __launch_bounds__(BDIM) void nnue_fused_f(
    const float* __restrict__ us,
    const float* __restrict__ them,
    const int*   __restrict__ wi,
    const float* __restrict__ wv,
    const int*   __restrict__ bi,
    const float* __restrict__ bvv,
    const int*   __restrict__ lsi,
    const float* __restrict__ W_ft,
    const float* __restrict__ b_ft,
    const float* __restrict__ W1,
    const float* __restrict__ b1,
    const float* __restrict__ W2,
    const float* __restrict__ b2,
    const float* __restrict__ W3,
    const float* __restrict__ b3,
    float* __restrict__ out)
{
    const int b = blockIdx.x;
    const int t = threadIdx.x;

    __shared__ int   s_idx[2 * K];
    __shared__ float s_val[2 * K];
    __shared__ float s_l0[2 * L1];
    __shared__ float s_red[4 * 16];
    __shared__ float s_v[2 * L2C];
    __shared__ float s_p2[L3C];
    __shared__ float s_l1f;

    if (t < K)          { s_idx[t] = wi[b * K + t];        s_val[t] = wv[b * K + t]; }
    else if (t < 2 * K) { s_idx[t] = bi[b * K + (t - K)];  s_val[t] = bvv[b * K + (t - K)]; }
    __syncthreads();

    const int c4 = t * 4;
    float4 accW = *(const float4*)(b_ft + c4);
    float4 accB = accW;

    #pragma unroll 8
    for (int k = 0; k < K; ++k) {
        const float  vwk = s_val[k];
        const float  vbk = s_val[K + k];
        const float4 rw  = *(const float4*)(W_ft + ((long)s_idx[k]     << 10) + c4);
        const float4 rb  = *(const float4*)(W_ft + ((long)s_idx[K + k] << 10) + c4);
        accW.x = fmaf(vwk, rw.x, accW.x);
        accW.y = fmaf(vwk, rw.y, accW.y);
        accW.z = fmaf(vwk, rw.z, accW.z);
        accW.w = fmaf(vwk, rw.w, accW.w);
        accB.x = fmaf(vbk, rb.x, accB.x);
        accB.y = fmaf(vbk, rb.y, accB.y);
        accB.z = fmaf(vbk, rb.z, accB.z);
        accB.w = fmaf(vbk, rb.w, accB.w);
    }

    const float u  = us[b];
    const float th = them[b];
    float4 A, Bv;
    A.x  = clip01(u * accW.x + th * accB.x);
    A.y  = clip01(u * accW.y + th * accB.y);
    A.z  = clip01(u * accW.z + th * accB.z);
    A.w  = clip01(u * accW.w + th * accB.w);
    Bv.x = clip01(u * accB.x + th * accW.x);
    Bv.y = clip01(u * accB.y + th * accW.y);
    Bv.z = clip01(u * accB.z + th * accW.z);
    Bv.w = clip01(u * accB.w + th * accW.w);
    *(float4*)(s_l0 + c4)      = A;
    *(float4*)(s_l0 + L1 + c4) = Bv;
    __syncthreads();

    const int   idx = lsi[b];
    const float cc  = 127.0f / 128.0f;

    float p[16];
    #pragma unroll
    for (int j = 0; j < 16; ++j) p[j] = 0.0f;

    const float* W1sel = W1 + idx * (L2C + 1);
    #pragma unroll
    for (int q = 0; q < 4; ++q) {
        const int e = c4 + q;
        float l0p;
        if (e < 512) l0p = s_l0[e] * s_l0[e + 512];
        else         l0p = s_l0[e + 512] * s_l0[e + 1024];
        l0p *= cc;
        const float* wrow = W1sel + e * W1COLS;
        #pragma unroll
        for (int j = 0; j < 16; ++j) p[j] = fmaf(l0p, wrow[j], p[j]);
    }

    const int lane = t & 63;
    const int wid  = t >> 6;
    #pragma unroll
    for (int j = 0; j < 16; ++j) {
        float v = p[j];
        v += __shfl_down(v, 32);
        v += __shfl_down(v, 16);
        v += __shfl_down(v, 8);
        v += __shfl_down(v, 4);
        v += __shfl_down(v, 2);
        v += __shfl_down(v, 1);
        if (lane == 0) s_red[wid * 16 + j] = v;
    }
    __syncthreads();

    if (t < 16) {
        float x1 = s_red[t] + s_red[16 + t] + s_red[32 + t] + s_red[48 + t]
                 + b1[idx * (L2C + 1) + t];
        if (t == 15) {
            s_l1f = x1;
        } else {
            float cx = clip01(x1);
            s_v[t]       = cx * cx * cc;
            s_v[L2C + t] = cx * cc;
        }
    }
    __syncthreads();

    if (t < L3C) {
        float acc = b2[idx * L3C + t];
        #pragma unroll
        for (int r = 0; r < 2 * L2C; ++r)
            acc = fmaf(s_v[r], W2[r * W2COLS + idx * L3C + t], acc);
        s_p2[t] = clip01(acc) * W3[t * COUNT + idx];
    }
    __syncthreads();

    if (t == 0) {
        float s = 0.0f;
        #pragma unroll
        for (int m = 0; m < L3C; ++m) s += s_p2[m];
        out[b] = s + b3[idx] + s_l1f;
    }
}

extern "C" void kernel_launch(void* const* d_in, const int* in_sizes, int n_in,
                              void* d_out, int out_size, void* d_ws, size_t ws_size,
                              hipStream_t stream) {
    const float* us   = (const float*)d_in[0];
    const float* them = (const float*)d_in[1];
    const int*   wi   = (const int*)  d_in[2];
    const float* wv   = (const float*)d_in[3];
    const int*   bi   = (const int*)  d_in[4];
    const float* bv   = (const float*)d_in[5];
    const int*   lsi  = (const int*)  d_in[6];
    const float* W_ft = (const float*)d_in[7];
    const float* b_ft = (const float*)d_in[8];
    const float* W1   = (const float*)d_in[9];
    const float* b1   = (const float*)d_in[10];
    const float* W2   = (const float*)d_in[11];
    const float* b2   = (const float*)d_in[12];
    const float* W3   = (const float*)d_in[13];
    const float* b3   = (const float*)d_in[14];
    float*       out  = (float*)d_out;

    const int Bn = in_sizes[0]; // 4096 batch rows
    const size_t qTableBytes = (size_t)NF * L1;                  // 23.1 MB
    const size_t needed      = qTableBytes + (size_t)NF * sizeof(float);

    if (ws_size >= needed) {
        unsigned char* Wq  = (unsigned char*)d_ws;
        float*         scl = (float*)((char*)d_ws + qTableBytes);
        quant_w_ft<<<(NF + 3) / 4, 256, 0, stream>>>(W_ft, Wq, scl, NF);
        nnue_fused_q<<<Bn, BDIM, 0, stream>>>(us, them, wi, wv, bi, bv, lsi,
                                              Wq, scl, b_ft, W1, b1, W2, b2, W3, b3, out);
    } else {
        nnue_fused_f<<<Bn, BDIM, 0, stream>>>(us, them, wi, wv, bi, bv, lsi,
                                              W_ft, b_ft, W1, b1, W2, b2, W3, b3, out);
    }
}